// Round 6
// baseline (1584.275 us; speedup 1.0000x reference)
//
#include <hip/hip_runtime.h>
#include <stdint.h>

typedef short bf16x8 __attribute__((ext_vector_type(8)));
typedef float f32x4  __attribute__((ext_vector_type(4)));
typedef uint32_t u32;

#define NSAMP  32768
#define D      512
#define RPB    16
#define NLAYER 7
#define KSN    16
#define WL_U32 131072                // u32 per packed layer

union U4B { uint4 u; u32 w[4]; bf16x8 s; };
__device__ __forceinline__ bf16x8 as_frag(uint4 v) { U4B c; c.u = v; return c.s; }

__device__ __forceinline__ u32 bfr(float f) {               // RNE bf16 bits
    u32 b = __float_as_uint(f);
    return (b + 0x7fffu + ((b >> 16) & 1u)) >> 16;
}
__device__ __forceinline__ float bf2f(u32 h) { return __uint_as_float(h << 16); }
__device__ __forceinline__ u32 packpair(float v) {          // hi | lo<<16
    u32 h = bfr(v);
    u32 l = bfr(v - bf2f(h));
    return h | (l << 16);
}
__device__ __forceinline__ float fast_tanh(float z) {       // inf-safe both tails
    const float e = __expf(2.f * z);
    return 1.f - 2.f / (e + 1.f);
}

// ---- prep: pack Wh[L][k][n] -> B-fragment-ordered bf16 hi/lo tensors ----
// 16B unit idx4 = ((L*16+ks)*512 + n)*4 + half ; holds k = ks*32+half*8+{0..7}, col n
__global__ void pack_weights(const float* __restrict__ Wh,
                             u32* __restrict__ whi, u32* __restrict__ wlo) {
    const int L    = blockIdx.x >> 4;
    const int ks   = blockIdx.x & 15;
    const int lane = threadIdx.x & 63;
    const int half = threadIdx.x >> 6;                       // 0..3
    const float* src = Wh + (size_t)L * D * D + (size_t)(ks * 32 + half * 8) * D;
    for (int nb = 0; nb < D; nb += 64) {
        const int n = nb + lane;
        float v[8];
        #pragma unroll
        for (int i = 0; i < 8; ++i) v[i] = src[(size_t)i * D + n];
        u32 hi[4], lo[4];
        #pragma unroll
        for (int j = 0; j < 4; ++j) {
            u32 h0 = bfr(v[2*j]),   l0 = bfr(v[2*j]   - bf2f(h0));
            u32 h1 = bfr(v[2*j+1]), l1 = bfr(v[2*j+1] - bf2f(h1));
            hi[j] = h0 | (h1 << 16);
            lo[j] = l0 | (l1 << 16);
        }
        const size_t idx4 = (size_t)((L * 16 + ks) * 512 + n) * 4 + half;
        *(uint4*)(whi + idx4 * 4) = *(uint4*)hi;
        *(uint4*)(wlo + idx4 * 4) = *(uint4*)lo;
    }
}

// ---- main: 16 waves = 16 col-groups (32 cols each), each wave does all 4 row-tiles ----
// h rows: 3-product split-bf16 (2^-17); J rows: 2-product (A rounded once to bf16).
// LDS 80 KB -> 2 blocks/CU: block A's epilogue overlaps block B's K-loop.
__global__ __launch_bounds__(1024, 8)
void mlp_curl_mfma(const float* __restrict__ x,
                   const float* __restrict__ W0,
                   const float* __restrict__ b0,
                   const float* __restrict__ bhid,
                   const float* __restrict__ Wf,
                   const u32* __restrict__ whi,
                   const u32* __restrict__ wlo,
                   float* __restrict__ out)
{
    // A fragments in MFMA order: uint4 index (R*16+ks)*64 + fraglane,
    // fraglane = (k>>3)*16 + row ; within uint4, bf16 for k&7 at byte (k&7)*2.
    __shared__ uint4 AHi[4096];      // 64 KB: all 4 row-tiles
    __shared__ uint4 ALo[1024];      // 16 KB: lo of h rows only (R=0)

    const int t    = threadIdx.x;
    const int g    = t >> 6, lane = t & 63;
    const int lrow = lane & 15, lq = lane >> 4;
    const int cg   = g;                       // col-group: cols [cg*32, cg*32+32)
    const int n0   = blockIdx.x * RPB;

    // ---------- init: wave g fills tiles (R = g>>2, ks = (g&3)*4 .. +3) ----------
    {
        const int R  = g >> 2, c4 = g & 3;
        const float4 xv = *(const float4*)(x + (size_t)(n0 + lrow) * 4);
        #pragma unroll
        for (int ksl = 0; ksl < 4; ++ksl) {
            const int ks = c4 * 4 + ksl;
            const int c0 = ks * 32 + lq * 8;
            float v[8];
            if (R == 0) {
                #pragma unroll
                for (int j = 0; j < 8; ++j)
                    v[j] = b0[c0 + j]
                         + xv.x * W0[c0 + j]         + xv.y * W0[D + c0 + j]
                         + xv.z * W0[2 * D + c0 + j] + xv.w * W0[3 * D + c0 + j];
                u32 pp[8];
                #pragma unroll
                for (int j = 0; j < 8; ++j) pp[j] = packpair(v[j]);
                uint4 hi, lo;
                hi.x = (pp[0] & 0xffffu) | (pp[1] << 16);  lo.x = (pp[0] >> 16) | (pp[1] & 0xffff0000u);
                hi.y = (pp[2] & 0xffffu) | (pp[3] << 16);  lo.y = (pp[2] >> 16) | (pp[3] & 0xffff0000u);
                hi.z = (pp[4] & 0xffffu) | (pp[5] << 16);  lo.z = (pp[4] >> 16) | (pp[5] & 0xffff0000u);
                hi.w = (pp[6] & 0xffffu) | (pp[7] << 16);  lo.w = (pp[6] >> 16) | (pp[7] & 0xffff0000u);
                AHi[ks * 64 + lane] = hi;
                ALo[ks * 64 + lane] = lo;
            } else {
                const float* wr = W0 + (size_t)(R - 1) * D;
                #pragma unroll
                for (int j = 0; j < 8; ++j) v[j] = wr[c0 + j];
                uint4 hi;
                hi.x = bfr(v[0]) | (bfr(v[1]) << 16);
                hi.y = bfr(v[2]) | (bfr(v[3]) << 16);
                hi.z = bfr(v[4]) | (bfr(v[5]) << 16);
                hi.w = bfr(v[6]) | (bfr(v[7]) << 16);
                AHi[(R * 16 + ks) * 64 + lane] = hi;
            }
        }
    }
    __syncthreads();

    // per-lane B offsets (u32 units) within a ks-slab, for the wave's two 16-col tiles
    const u32 boff0 = ((u32)(cg * 32 + lrow) * 4 + lq) * 4;
    const u32 boff1 = boff0 + 256;

    for (int L = 0; L < NLAYER; ++L) {
        const u32* __restrict__ whiL = whi + (size_t)L * WL_U32;
        const u32* __restrict__ wloL = wlo + (size_t)L * WL_U32;
        f32x4 acc[4][2];
        #pragma unroll
        for (int R = 0; R < 4; ++R) { acc[R][0] = (f32x4)0.f; acc[R][1] = (f32x4)0.f; }

        uint4 Bh[2][2], Bl[2][2];
        Bh[0][0] = *(const uint4*)(whiL + boff0);
        Bh[0][1] = *(const uint4*)(whiL + boff1);
        Bl[0][0] = *(const uint4*)(wloL + boff0);
        Bl[0][1] = *(const uint4*)(wloL + boff1);

        #pragma unroll
        for (int ks = 0; ks < KSN; ++ks) {
            const int cur = ks & 1, nxt = cur ^ 1;
            if (ks + 1 < KSN) {                      // prefetch next ks-slab
                const size_t off = (size_t)(ks + 1) * 8192;
                Bh[nxt][0] = *(const uint4*)(whiL + off + boff0);
                Bh[nxt][1] = *(const uint4*)(whiL + off + boff1);
                Bl[nxt][0] = *(const uint4*)(wloL + off + boff0);
                Bl[nxt][1] = *(const uint4*)(wloL + off + boff1);
            }
            // R = 0 (h rows): 3-product
            {
                const bf16x8 a_hi = as_frag(AHi[ks * 64 + lane]);
                const bf16x8 a_lo = as_frag(ALo[ks * 64 + lane]);
                #pragma unroll
                for (int ct = 0; ct < 2; ++ct) {
                    const bf16x8 bh_ = as_frag(Bh[cur][ct]);
                    const bf16x8 bl_ = as_frag(Bl[cur][ct]);
                    acc[0][ct] = __builtin_amdgcn_mfma_f32_16x16x32_bf16(a_lo, bh_, acc[0][ct], 0, 0, 0);
                    acc[0][ct] = __builtin_amdgcn_mfma_f32_16x16x32_bf16(a_hi, bl_, acc[0][ct], 0, 0, 0);
                    acc[0][ct] = __builtin_amdgcn_mfma_f32_16x16x32_bf16(a_hi, bh_, acc[0][ct], 0, 0, 0);
                }
            }
            // R = 1..3 (J rows): 2-product (A single-rounded bf16, B split)
            #pragma unroll
            for (int R = 1; R < 4; ++R) {
                const bf16x8 a_hi = as_frag(AHi[(R * 16 + ks) * 64 + lane]);
                #pragma unroll
                for (int ct = 0; ct < 2; ++ct) {
                    const bf16x8 bh_ = as_frag(Bh[cur][ct]);
                    const bf16x8 bl_ = as_frag(Bl[cur][ct]);
                    acc[R][ct] = __builtin_amdgcn_mfma_f32_16x16x32_bf16(a_hi, bl_, acc[R][ct], 0, 0, 0);
                    acc[R][ct] = __builtin_amdgcn_mfma_f32_16x16x32_bf16(a_hi, bh_, acc[R][ct], 0, 0, 0);
                }
            }
        }
        __syncthreads();                 // all A-frag reads of layer L done

        // tanh' from the wave's OWN h-tiles (same lane, same q -> register handoff)
        float tp[2][4];
        #pragma unroll
        for (int ct = 0; ct < 2; ++ct) {
            const int col = cg * 32 + ct * 16 + lrow;
            const float bias = bhid[(size_t)L * D + col];
            const int k = ct * 16 + lrow;
            #pragma unroll
            for (int q = 0; q < 4; ++q) {
                const float h = fast_tanh(acc[0][ct][q] + bias);
                tp[ct][q] = (1.f - h) * (1.f + h);
                if (L < NLAYER - 1) {    // scatter h into frag tile (R=0, ks=cg)
                    const u32 pp = packpair(h);
                    const u32 byte = ((u32)((cg * 64) + (k >> 3) * 16 + (lq * 4 + q)) << 4)
                                   | ((u32)(k & 7) << 1);
                    *(uint16_t*)((char*)AHi + byte) = (uint16_t)(pp & 0xffffu);
                    *(uint16_t*)((char*)ALo + byte) = (uint16_t)(pp >> 16);
                }
            }
        }

        if (L < NLAYER - 1) {            // J-phase: scale + scatter hi-only into (R, ks=cg)
            #pragma unroll
            for (int R = 1; R < 4; ++R)
                #pragma unroll
                for (int ct = 0; ct < 2; ++ct) {
                    const int k = ct * 16 + lrow;
                    #pragma unroll
                    for (int q = 0; q < 4; ++q) {
                        const u32 hb = bfr(acc[R][ct][q] * tp[ct][q]);
                        const u32 byte = ((u32)(((R * 16 + cg) * 64) + (k >> 3) * 16 + (lq * 4 + q)) << 4)
                                       | ((u32)(k & 7) << 1);
                        *(uint16_t*)((char*)AHi + byte) = (uint16_t)hb;
                    }
                }
        } else {                         // final: Jout partials over this wave's 32 cols
            float part[3][4][4];
            #pragma unroll
            for (int i = 0; i < 3; ++i)
                #pragma unroll
                for (int q = 0; q < 4; ++q)
                    #pragma unroll
                    for (int o = 0; o < 4; ++o) part[i][q][o] = 0.f;
            #pragma unroll
            for (int ct = 0; ct < 2; ++ct) {
                const int col = cg * 32 + ct * 16 + lrow;
                const float4 wf = *(const float4*)(Wf + (size_t)col * 4);
                #pragma unroll
                for (int R = 1; R < 4; ++R)
                    #pragma unroll
                    for (int q = 0; q < 4; ++q) {
                        const float jv = acc[R][ct][q] * tp[ct][q];
                        part[R-1][q][0] += jv * wf.x;
                        part[R-1][q][1] += jv * wf.y;
                        part[R-1][q][2] += jv * wf.z;
                        part[R-1][q][3] += jv * wf.w;
                    }
            }
            #pragma unroll
            for (int m = 1; m <= 8; m <<= 1)
                #pragma unroll
                for (int i = 0; i < 3; ++i)
                    #pragma unroll
                    for (int q = 0; q < 4; ++q)
                        #pragma unroll
                        for (int o = 0; o < 4; ++o)
                            part[i][q][o] += __shfl_xor(part[i][q][o], m);
            if (lrow == 0) {             // JT[cg][i][s][o] in dead AHi space
                float* JT = (float*)AHi;
                #pragma unroll
                for (int i = 0; i < 3; ++i)
                    #pragma unroll
                    for (int q = 0; q < 4; ++q) {
                        const int s = lq * 4 + q;
                        #pragma unroll
                        for (int o = 0; o < 4; ++o)
                            JT[((cg * 3 + i) * 16 + s) * 4 + o] = part[i][q][o];
                    }
            }
        }
        __syncthreads();
    }

    // ---------- curl combination (sum JT over the 16 col-groups) ----------
    if (t < RPB * 6) {
        const float* JT = (const float*)AHi;
        const int s = t / 6, c = t % 6;
        float J[3][4];
        #pragma unroll
        for (int i = 0; i < 3; ++i)
            #pragma unroll
            for (int o = 0; o < 4; ++o) {
                float v = 0.f;
                for (int w = 0; w < 16; ++w) v += JT[((w * 3 + i) * 16 + s) * 4 + o];
                J[i][o] = v;
            }
        float v;
        if      (c == 0) v = J[1][2] - J[2][1];
        else if (c == 1) v = J[2][0] - J[0][2];
        else if (c == 2) v = J[0][1] - J[1][0];
        else if (c == 3) v = J[0][3];
        else if (c == 4) v = J[1][3];
        else             v = J[2][3];
        out[(size_t)(n0 + s) * 6 + c] = v;
    }
}

extern "C" void kernel_launch(void* const* d_in, const int* in_sizes, int n_in,
                              void* d_out, int out_size, void* d_ws, size_t ws_size,
                              hipStream_t stream) {
    const float* x  = (const float*)d_in[0];
    const float* W0 = (const float*)d_in[1];
    const float* b0 = (const float*)d_in[2];
    const float* Wh = (const float*)d_in[3];
    const float* bh = (const float*)d_in[4];
    const float* Wf = (const float*)d_in[5];
    u32* whi = (u32*)d_ws;
    u32* wlo = whi + (size_t)NLAYER * WL_U32;
    pack_weights<<<NLAYER * 16, 256, 0, stream>>>(Wh, whi, wlo);
    mlp_curl_mfma<<<NSAMP / RPB, 1024, 0, stream>>>(x, W0, b0, bh, Wf, whi, wlo, (float*)d_out);
}

// Round 7
// 1112.067 us; speedup vs baseline: 1.4246x; 1.4246x over previous
//
#include <hip/hip_runtime.h>
#include <stdint.h>

typedef short bf16x8 __attribute__((ext_vector_type(8)));
typedef float f32x4  __attribute__((ext_vector_type(4)));
typedef uint32_t u32;

#define NSAMP  32768
#define D      512
#define RPB    16
#define NLAYER 7
#define KSN    16
#define WL_U32 131072                // u32 per packed layer

union U4B { uint4 u; u32 w[4]; bf16x8 s; };
__device__ __forceinline__ bf16x8 as_frag(uint4 v) { U4B c; c.u = v; return c.s; }

__device__ __forceinline__ u32 bfr(float f) {               // RNE bf16 bits
    u32 b = __float_as_uint(f);
    return (b + 0x7fffu + ((b >> 16) & 1u)) >> 16;
}
__device__ __forceinline__ float bf2f(u32 h) { return __uint_as_float(h << 16); }
__device__ __forceinline__ u32 packpair(float v) {          // hi | lo<<16
    u32 h = bfr(v);
    u32 l = bfr(v - bf2f(h));
    return h | (l << 16);
}
__device__ __forceinline__ float fast_tanh(float z) {       // inf-safe both tails
    const float e = __expf(2.f * z);
    return 1.f - 2.f / (e + 1.f);
}

// ---- prep: pack Wh[L][k][n] -> B-fragment-ordered bf16 hi/lo tensors ----
// 16B unit idx4 = ((L*16+ks)*512 + n)*4 + half ; holds k = ks*32+half*8+{0..7}, col n
__global__ void pack_weights(const float* __restrict__ Wh,
                             u32* __restrict__ whi, u32* __restrict__ wlo) {
    const int L    = blockIdx.x >> 4;
    const int ks   = blockIdx.x & 15;
    const int lane = threadIdx.x & 63;
    const int half = threadIdx.x >> 6;                       // 0..3
    const float* src = Wh + (size_t)L * D * D + (size_t)(ks * 32 + half * 8) * D;
    for (int nb = 0; nb < D; nb += 64) {
        const int n = nb + lane;
        float v[8];
        #pragma unroll
        for (int i = 0; i < 8; ++i) v[i] = src[(size_t)i * D + n];
        u32 hi[4], lo[4];
        #pragma unroll
        for (int j = 0; j < 4; ++j) {
            u32 h0 = bfr(v[2*j]),   l0 = bfr(v[2*j]   - bf2f(h0));
            u32 h1 = bfr(v[2*j+1]), l1 = bfr(v[2*j+1] - bf2f(h1));
            hi[j] = h0 | (h1 << 16);
            lo[j] = l0 | (l1 << 16);
        }
        const size_t idx4 = (size_t)((L * 16 + ks) * 512 + n) * 4 + half;
        *(uint4*)(whi + idx4 * 4) = *(uint4*)hi;
        *(uint4*)(wlo + idx4 * 4) = *(uint4*)lo;
    }
}

// ---- main: 16 waves = 16 col-groups (32 cols each), each wave does all 4 row-tiles ----
// h rows: 3-product split-bf16; J rows: 2-product. 80 KB LDS -> 2 blocks/CU;
// register-lean: single-buffered B, per-i final reduce, no forced launch bound.
__global__ __launch_bounds__(1024)
void mlp_curl_mfma(const float* __restrict__ x,
                   const float* __restrict__ W0,
                   const float* __restrict__ b0,
                   const float* __restrict__ bhid,
                   const float* __restrict__ Wf,
                   const u32* __restrict__ whi,
                   const u32* __restrict__ wlo,
                   float* __restrict__ out)
{
    // A fragments in MFMA order: uint4 index (R*16+ks)*64 + fraglane,
    // fraglane = (k>>3)*16 + row ; within uint4, bf16 for k&7 at byte (k&7)*2.
    __shared__ uint4 AHi[4096];      // 64 KB: all 4 row-tiles
    __shared__ uint4 ALo[1024];      // 16 KB: lo of h rows only (R=0)

    const int t    = threadIdx.x;
    const int g    = t >> 6, lane = t & 63;
    const int lrow = lane & 15, lq = lane >> 4;
    const int cg   = g;                       // col-group: cols [cg*32, cg*32+32)
    const int n0   = blockIdx.x * RPB;

    // ---------- init: wave g fills tiles (R = g>>2, ks = (g&3)*4 .. +3) ----------
    {
        const int R  = g >> 2, c4 = g & 3;
        const float4 xv = *(const float4*)(x + (size_t)(n0 + lrow) * 4);
        #pragma unroll
        for (int ksl = 0; ksl < 4; ++ksl) {
            const int ks = c4 * 4 + ksl;
            const int c0 = ks * 32 + lq * 8;
            float v[8];
            if (R == 0) {
                #pragma unroll
                for (int j = 0; j < 8; ++j)
                    v[j] = b0[c0 + j]
                         + xv.x * W0[c0 + j]         + xv.y * W0[D + c0 + j]
                         + xv.z * W0[2 * D + c0 + j] + xv.w * W0[3 * D + c0 + j];
                u32 pp[8];
                #pragma unroll
                for (int j = 0; j < 8; ++j) pp[j] = packpair(v[j]);
                uint4 hi, lo;
                hi.x = (pp[0] & 0xffffu) | (pp[1] << 16);  lo.x = (pp[0] >> 16) | (pp[1] & 0xffff0000u);
                hi.y = (pp[2] & 0xffffu) | (pp[3] << 16);  lo.y = (pp[2] >> 16) | (pp[3] & 0xffff0000u);
                hi.z = (pp[4] & 0xffffu) | (pp[5] << 16);  lo.z = (pp[4] >> 16) | (pp[5] & 0xffff0000u);
                hi.w = (pp[6] & 0xffffu) | (pp[7] << 16);  lo.w = (pp[6] >> 16) | (pp[7] & 0xffff0000u);
                AHi[ks * 64 + lane] = hi;
                ALo[ks * 64 + lane] = lo;
            } else {
                const float* wr = W0 + (size_t)(R - 1) * D;
                #pragma unroll
                for (int j = 0; j < 8; ++j) v[j] = wr[c0 + j];
                uint4 hi;
                hi.x = bfr(v[0]) | (bfr(v[1]) << 16);
                hi.y = bfr(v[2]) | (bfr(v[3]) << 16);
                hi.z = bfr(v[4]) | (bfr(v[5]) << 16);
                hi.w = bfr(v[6]) | (bfr(v[7]) << 16);
                AHi[(R * 16 + ks) * 64 + lane] = hi;
            }
        }
    }
    __syncthreads();

    // per-lane B offsets (u32 units) within a ks-slab, for the wave's two 16-col tiles
    const u32 boff0 = ((u32)(cg * 32 + lrow) * 4 + lq) * 4;
    const u32 boff1 = boff0 + 256;

    for (int L = 0; L < NLAYER; ++L) {
        const u32* __restrict__ whiL = whi + (size_t)L * WL_U32;
        const u32* __restrict__ wloL = wlo + (size_t)L * WL_U32;
        f32x4 acc[4][2];
        #pragma unroll
        for (int R = 0; R < 4; ++R) { acc[R][0] = (f32x4)0.f; acc[R][1] = (f32x4)0.f; }

        #pragma unroll 2
        for (int ks = 0; ks < KSN; ++ks) {
            const size_t off = (size_t)ks * 8192;
            const uint4 Bh0 = *(const uint4*)(whiL + off + boff0);
            const uint4 Bh1 = *(const uint4*)(whiL + off + boff1);
            const uint4 Bl0 = *(const uint4*)(wloL + off + boff0);
            const uint4 Bl1 = *(const uint4*)(wloL + off + boff1);
            // R = 0 (h rows): 3-product
            {
                const bf16x8 a_hi = as_frag(AHi[ks * 64 + lane]);
                const bf16x8 a_lo = as_frag(ALo[ks * 64 + lane]);
                const bf16x8 b0h = as_frag(Bh0), b0l = as_frag(Bl0);
                const bf16x8 b1h = as_frag(Bh1), b1l = as_frag(Bl1);
                acc[0][0] = __builtin_amdgcn_mfma_f32_16x16x32_bf16(a_lo, b0h, acc[0][0], 0, 0, 0);
                acc[0][0] = __builtin_amdgcn_mfma_f32_16x16x32_bf16(a_hi, b0l, acc[0][0], 0, 0, 0);
                acc[0][0] = __builtin_amdgcn_mfma_f32_16x16x32_bf16(a_hi, b0h, acc[0][0], 0, 0, 0);
                acc[0][1] = __builtin_amdgcn_mfma_f32_16x16x32_bf16(a_lo, b1h, acc[0][1], 0, 0, 0);
                acc[0][1] = __builtin_amdgcn_mfma_f32_16x16x32_bf16(a_hi, b1l, acc[0][1], 0, 0, 0);
                acc[0][1] = __builtin_amdgcn_mfma_f32_16x16x32_bf16(a_hi, b1h, acc[0][1], 0, 0, 0);
            }
            // R = 1..3 (J rows): 2-product (A single-rounded bf16, B split)
            #pragma unroll
            for (int R = 1; R < 4; ++R) {
                const bf16x8 a_hi = as_frag(AHi[(R * 16 + ks) * 64 + lane]);
                const bf16x8 b0h = as_frag(Bh0), b0l = as_frag(Bl0);
                const bf16x8 b1h = as_frag(Bh1), b1l = as_frag(Bl1);
                acc[R][0] = __builtin_amdgcn_mfma_f32_16x16x32_bf16(a_hi, b0l, acc[R][0], 0, 0, 0);
                acc[R][0] = __builtin_amdgcn_mfma_f32_16x16x32_bf16(a_hi, b0h, acc[R][0], 0, 0, 0);
                acc[R][1] = __builtin_amdgcn_mfma_f32_16x16x32_bf16(a_hi, b1l, acc[R][1], 0, 0, 0);
                acc[R][1] = __builtin_amdgcn_mfma_f32_16x16x32_bf16(a_hi, b1h, acc[R][1], 0, 0, 0);
            }
        }
        __syncthreads();                 // all A-frag reads of layer L done

        // tanh' from the wave's OWN h-tiles (same lane, same q -> register handoff)
        float tp[2][4];
        #pragma unroll
        for (int ct = 0; ct < 2; ++ct) {
            const int col = cg * 32 + ct * 16 + lrow;
            const float bias = bhid[(size_t)L * D + col];
            const int k = ct * 16 + lrow;
            #pragma unroll
            for (int q = 0; q < 4; ++q) {
                const float h = fast_tanh(acc[0][ct][q] + bias);
                tp[ct][q] = (1.f - h) * (1.f + h);
                if (L < NLAYER - 1) {    // scatter h into frag tile (R=0, ks=cg)
                    const u32 pp = packpair(h);
                    const u32 byte = ((u32)((cg * 64) + (k >> 3) * 16 + (lq * 4 + q)) << 4)
                                   | ((u32)(k & 7) << 1);
                    *(uint16_t*)((char*)AHi + byte) = (uint16_t)(pp & 0xffffu);
                    *(uint16_t*)((char*)ALo + byte) = (uint16_t)(pp >> 16);
                }
            }
        }

        if (L < NLAYER - 1) {            // J-phase: scale + scatter hi-only into (R, ks=cg)
            #pragma unroll
            for (int R = 1; R < 4; ++R)
                #pragma unroll
                for (int ct = 0; ct < 2; ++ct) {
                    const int k = ct * 16 + lrow;
                    #pragma unroll
                    for (int q = 0; q < 4; ++q) {
                        const u32 hb = bfr(acc[R][ct][q] * tp[ct][q]);
                        const u32 byte = ((u32)(((R * 16 + cg) * 64) + (k >> 3) * 16 + (lq * 4 + q)) << 4)
                                       | ((u32)(k & 7) << 1);
                        *(uint16_t*)((char*)AHi + byte) = (uint16_t)hb;
                    }
                }
        } else {                         // final: Jout partials, one i at a time (16 regs)
            #pragma unroll
            for (int i = 0; i < 3; ++i) {
                float Jrow[4][4];
                #pragma unroll
                for (int q = 0; q < 4; ++q)
                    #pragma unroll
                    for (int o = 0; o < 4; ++o) Jrow[q][o] = 0.f;
                #pragma unroll
                for (int ct = 0; ct < 2; ++ct) {
                    const int col = cg * 32 + ct * 16 + lrow;
                    const float4 wf = *(const float4*)(Wf + (size_t)col * 4);
                    #pragma unroll
                    for (int q = 0; q < 4; ++q) {
                        const float jv = acc[i + 1][ct][q] * tp[ct][q];
                        Jrow[q][0] += jv * wf.x;
                        Jrow[q][1] += jv * wf.y;
                        Jrow[q][2] += jv * wf.z;
                        Jrow[q][3] += jv * wf.w;
                    }
                }
                #pragma unroll
                for (int m = 1; m <= 8; m <<= 1)
                    #pragma unroll
                    for (int q = 0; q < 4; ++q)
                        #pragma unroll
                        for (int o = 0; o < 4; ++o)
                            Jrow[q][o] += __shfl_xor(Jrow[q][o], m);
                if (lrow == 0) {         // JT[cg][i][s][o] in dead AHi space
                    float* JT = (float*)AHi;
                    #pragma unroll
                    for (int q = 0; q < 4; ++q) {
                        const int s = lq * 4 + q;
                        #pragma unroll
                        for (int o = 0; o < 4; ++o)
                            JT[((cg * 3 + i) * 16 + s) * 4 + o] = Jrow[q][o];
                    }
                }
            }
        }
        __syncthreads();
    }

    // ---------- curl combination (sum JT over the 16 col-groups) ----------
    if (t < RPB * 6) {
        const float* JT = (const float*)AHi;
        const int s = t / 6, c = t % 6;
        float J[3][4];
        #pragma unroll
        for (int i = 0; i < 3; ++i)
            #pragma unroll
            for (int o = 0; o < 4; ++o) {
                float v = 0.f;
                for (int w = 0; w < 16; ++w) v += JT[((w * 3 + i) * 16 + s) * 4 + o];
                J[i][o] = v;
            }
        float v;
        if      (c == 0) v = J[1][2] - J[2][1];
        else if (c == 1) v = J[2][0] - J[0][2];
        else if (c == 2) v = J[0][1] - J[1][0];
        else if (c == 3) v = J[0][3];
        else if (c == 4) v = J[1][3];
        else             v = J[2][3];
        out[(size_t)(n0 + s) * 6 + c] = v;
    }
}

extern "C" void kernel_launch(void* const* d_in, const int* in_sizes, int n_in,
                              void* d_out, int out_size, void* d_ws, size_t ws_size,
                              hipStream_t stream) {
    const float* x  = (const float*)d_in[0];
    const float* W0 = (const float*)d_in[1];
    const float* b0 = (const float*)d_in[2];
    const float* Wh = (const float*)d_in[3];
    const float* bh = (const float*)d_in[4];
    const float* Wf = (const float*)d_in[5];
    u32* whi = (u32*)d_ws;
    u32* wlo = whi + (size_t)NLAYER * WL_U32;
    pack_weights<<<NLAYER * 16, 256, 0, stream>>>(Wh, whi, wlo);
    mlp_curl_mfma<<<NSAMP / RPB, 1024, 0, stream>>>(x, W0, b0, bh, Wf, whi, wlo, (float*)d_out);
}